// Round 2
// baseline (1580.177 us; speedup 1.0000x reference)
//
#include <hip/hip_runtime.h>

#define NN   100000
#define EE   1600000
#define HIDF 128
#define OUTF 64
#define KSEL 32

static __device__ __forceinline__ unsigned int sortable_key(float f) {
    unsigned int u = __float_as_uint(f);
    return (u & 0x80000000u) ? ~u : (u | 0x80000000u);
}

// ---------------- degree histogram ----------------
__global__ __launch_bounds__(256) void hist_kernel(const int* __restrict__ src,
                                                   const int* __restrict__ dst,
                                                   int* __restrict__ cnt_out,
                                                   int* __restrict__ cnt_in, int e) {
    int i = blockIdx.x * 256 + threadIdx.x;
    if (i < e) {
        atomicAdd(&cnt_out[src[i]], 1);
        atomicAdd(&cnt_in[dst[i]], 1);
    }
}

// ---------------- prefix scan (3 kernels) ----------------
__global__ __launch_bounds__(256) void scan_block(const int* __restrict__ cnt,
                                                  int* __restrict__ incl,
                                                  int* __restrict__ bsums, int n) {
    __shared__ int s[256];
    int t = threadIdx.x;
    int i = blockIdx.x * 256 + t;
    int v = (i < n) ? cnt[i] : 0;
    s[t] = v;
    __syncthreads();
    for (int off = 1; off < 256; off <<= 1) {
        int x = (t >= off) ? s[t - off] : 0;
        __syncthreads();
        s[t] += x;
        __syncthreads();
    }
    if (i < n) incl[i] = s[t];
    if (t == 255) bsums[blockIdx.x] = s[255];
}

__global__ __launch_bounds__(512) void scan_sums(const int* __restrict__ bsums,
                                                 int* __restrict__ boff, int nb) {
    __shared__ int s[512];
    int t = threadIdx.x;
    int v = (t < nb) ? bsums[t] : 0;
    s[t] = v;
    __syncthreads();
    for (int off = 1; off < 512; off <<= 1) {
        int x = (t >= off) ? s[t - off] : 0;
        __syncthreads();
        s[t] += x;
        __syncthreads();
    }
    boff[t] = s[t] - v;  // exclusive
}

__global__ __launch_bounds__(256) void finalize_offsets(const int* __restrict__ incl,
                                                        const int* __restrict__ boff,
                                                        const int* __restrict__ cnt_in,
                                                        const int* __restrict__ cnt_out,
                                                        int* __restrict__ row_off,
                                                        int* __restrict__ cursor,
                                                        float* __restrict__ dvo,
                                                        float* __restrict__ dvi, int n) {
    int i = blockIdx.x * 256 + threadIdx.x;
    if (i < n) {
        int ci = cnt_in[i];
        int val = incl[i] + boff[i >> 8];
        row_off[i + 1] = val;
        cursor[i] = val - ci;
        if (i == 0) row_off[0] = 0;
        dvo[i] = rsqrtf((float)max(cnt_out[i], 1));
        dvi[i] = rsqrtf((float)max(ci, 1));
    }
}

__global__ __launch_bounds__(256) void csr_fill(const int* __restrict__ src,
                                                const int* __restrict__ dst,
                                                int* __restrict__ cursor,
                                                int* __restrict__ csr, int e) {
    int i = blockIdx.x * 256 + threadIdx.x;
    if (i < e) {
        int d = dst[i];
        int pos = atomicAdd(&cursor[d], 1);
        csr[pos] = src[i];
    }
}

// ---------------- GEMM [n,128] x [128,128] + bias + ReLU -> dense ----------------
__global__ __launch_bounds__(256) void gemm_relu(const float* __restrict__ A,
                                                 const float* __restrict__ W,
                                                 const float* __restrict__ bias,
                                                 float* __restrict__ out, int n) {
    __shared__ float As[64][32];
    __shared__ float Ws[32][128];
    const int tid = threadIdx.x;
    const int rbase = blockIdx.x * 64;
    const int cc = tid & 31;          // cols 4*cc .. 4*cc+3
    const int r0 = (tid >> 5) * 8;    // 8 rows
    float acc[8][4];
#pragma unroll
    for (int i = 0; i < 8; ++i) { acc[i][0] = 0.f; acc[i][1] = 0.f; acc[i][2] = 0.f; acc[i][3] = 0.f; }

    for (int kc = 0; kc < 4; ++kc) {
        int lr = tid >> 3, c4 = (tid & 7) * 4;
#pragma unroll
        for (int p = 0; p < 2; ++p) {
            int row = lr + p * 32, gr = rbase + row;
            float4 v = make_float4(0.f, 0.f, 0.f, 0.f);
            if (gr < n) v = *(const float4*)(A + (size_t)gr * 128 + kc * 32 + c4);
            *(float4*)&As[row][c4] = v;
        }
        int wr = tid >> 5;
#pragma unroll
        for (int p = 0; p < 4; ++p) {
            int row = wr + p * 8;
            *(float4*)&Ws[row][cc * 4] = *(const float4*)(W + (size_t)(kc * 32 + row) * 128 + cc * 4);
        }
        __syncthreads();
#pragma unroll
        for (int k = 0; k < 32; k += 4) {
            float4 w0 = *(float4*)&Ws[k + 0][cc * 4];
            float4 w1 = *(float4*)&Ws[k + 1][cc * 4];
            float4 w2 = *(float4*)&Ws[k + 2][cc * 4];
            float4 w3 = *(float4*)&Ws[k + 3][cc * 4];
#pragma unroll
            for (int i = 0; i < 8; ++i) {
                float4 a = *(float4*)&As[r0 + i][k];
                acc[i][0] += a.x * w0.x + a.y * w1.x + a.z * w2.x + a.w * w3.x;
                acc[i][1] += a.x * w0.y + a.y * w1.y + a.z * w2.y + a.w * w3.y;
                acc[i][2] += a.x * w0.z + a.y * w1.z + a.z * w2.z + a.w * w3.z;
                acc[i][3] += a.x * w0.w + a.y * w1.w + a.z * w2.w + a.w * w3.w;
            }
        }
        __syncthreads();
    }
    float4 b4 = *(const float4*)(bias + cc * 4);
#pragma unroll
    for (int i = 0; i < 8; ++i) {
        int gr = rbase + r0 + i;
        if (gr < n) {
            float4 o = make_float4(fmaxf(acc[i][0] + b4.x, 0.f), fmaxf(acc[i][1] + b4.y, 0.f),
                                   fmaxf(acc[i][2] + b4.z, 0.f), fmaxf(acc[i][3] + b4.w, 0.f));
            *(float4*)(out + (size_t)gr * 128 + cc * 4) = o;
        }
    }
}

// ---------------- GEMM + bias + MaxK(top-32) -> sparse (vals scaled by deg_out^-1/2) ----------------
// LDS note: G is only live after the compute phase, so it unions over As/Ws:
// 32 KB total -> 5 blocks/CU (vs 56 KB -> 2 blocks/CU before).
__global__ __launch_bounds__(256) void gemm_maxk(const float* __restrict__ A,
                                                 const float* __restrict__ W,
                                                 const float* __restrict__ bias,
                                                 const float* __restrict__ dvout,
                                                 float* __restrict__ svals,
                                                 unsigned char* __restrict__ sidx, int n) {
    __shared__ union U {
        struct { float As[64][32]; float Ws[32][128]; } s;
        float G[64][128];
    } u;
    const int tid = threadIdx.x;
    const int rbase = blockIdx.x * 64;
    const int cc = tid & 31;
    const int r0 = (tid >> 5) * 8;
    float acc[8][4];
#pragma unroll
    for (int i = 0; i < 8; ++i) { acc[i][0] = 0.f; acc[i][1] = 0.f; acc[i][2] = 0.f; acc[i][3] = 0.f; }

    for (int kc = 0; kc < 4; ++kc) {
        int lr = tid >> 3, c4 = (tid & 7) * 4;
#pragma unroll
        for (int p = 0; p < 2; ++p) {
            int row = lr + p * 32, gr = rbase + row;
            float4 v = make_float4(0.f, 0.f, 0.f, 0.f);
            if (gr < n) v = *(const float4*)(A + (size_t)gr * 128 + kc * 32 + c4);
            *(float4*)&u.s.As[row][c4] = v;
        }
        int wr = tid >> 5;
#pragma unroll
        for (int p = 0; p < 4; ++p) {
            int row = wr + p * 8;
            *(float4*)&u.s.Ws[row][cc * 4] = *(const float4*)(W + (size_t)(kc * 32 + row) * 128 + cc * 4);
        }
        __syncthreads();
#pragma unroll
        for (int k = 0; k < 32; k += 4) {
            float4 w0 = *(float4*)&u.s.Ws[k + 0][cc * 4];
            float4 w1 = *(float4*)&u.s.Ws[k + 1][cc * 4];
            float4 w2 = *(float4*)&u.s.Ws[k + 2][cc * 4];
            float4 w3 = *(float4*)&u.s.Ws[k + 3][cc * 4];
#pragma unroll
            for (int i = 0; i < 8; ++i) {
                float4 a = *(float4*)&u.s.As[r0 + i][k];
                acc[i][0] += a.x * w0.x + a.y * w1.x + a.z * w2.x + a.w * w3.x;
                acc[i][1] += a.x * w0.y + a.y * w1.y + a.z * w2.y + a.w * w3.y;
                acc[i][2] += a.x * w0.z + a.y * w1.z + a.z * w2.z + a.w * w3.z;
                acc[i][3] += a.x * w0.w + a.y * w1.w + a.z * w2.w + a.w * w3.w;
            }
        }
        __syncthreads();
    }
    {
        float4 b4 = *(const float4*)(bias + cc * 4);
#pragma unroll
        for (int i = 0; i < 8; ++i) {
            float4 o = make_float4(acc[i][0] + b4.x, acc[i][1] + b4.y,
                                   acc[i][2] + b4.z, acc[i][3] + b4.w);
            *(float4*)&u.G[r0 + i][cc * 4] = o;
        }
    }
    __syncthreads();

    const int lane = tid & 63;
    const int wv = tid >> 6;  // 0..3, handles rows wv*16 .. wv*16+15
    const unsigned long long lt = (1ull << lane) - 1ull;

    for (int rr = 0; rr < 16; ++rr) {
        int row = wv * 16 + rr;
        int node = rbase + row;
        if (node >= n) break;  // wave-uniform
        float v0 = u.G[row][lane];
        float v1 = u.G[row][lane + 64];
        unsigned int k0 = sortable_key(v0), k1 = sortable_key(v1);
        // radix binary search for the 32nd-largest key T (== pref at end)
        unsigned int pref = 0u;
        for (int bit = 31; bit >= 0; --bit) {
            unsigned int cand = pref | (1u << bit);
            unsigned long long b0 = __ballot(k0 >= cand);
            unsigned long long b1 = __ballot(k1 >= cand);
            if (__popcll(b0) + __popcll(b1) >= KSEL) pref = cand;
        }
        unsigned long long g0 = __ballot(k0 > pref), g1 = __ballot(k1 > pref);
        unsigned long long e0 = __ballot(k0 == pref), e1 = __ballot(k1 == pref);
        int m = __popcll(g0) + __popcll(g1);
        int need = KSEL - m;  // ties at T: take lowest feature indices first (JAX top_k)
        float ds = dvout[node];
        int slot = -1;
        if (k0 > pref) slot = __popcll(g0 & lt);
        else if (k0 == pref) { int r = __popcll(e0 & lt); if (r < need) slot = m + r; }
        if (slot >= 0) {
            svals[(size_t)node * 32 + slot] = v0 * ds;
            sidx[(size_t)node * 32 + slot] = (unsigned char)lane;
        }
        slot = -1;
        if (k1 > pref) slot = __popcll(g0) + __popcll(g1 & lt);
        else if (k1 == pref) { int r = __popcll(e0) + __popcll(e1 & lt); if (r < need) slot = m + r; }
        if (slot >= 0) {
            svals[(size_t)node * 32 + slot] = v1 * ds;
            sidx[(size_t)node * 32 + slot] = (unsigned char)(lane + 64);
        }
    }
}

// ---------------- CSR aggregation: one wave per dst node, LDS accumulator ----------------
// 8 lanes per edge (float4/uchar4 loads) -> 8 edges concurrent per wave;
// 2-deep unroll -> 16 independent gathers in flight (was 2). Latency-bound fix.
__global__ __launch_bounds__(256) void agg_kernel(const float* __restrict__ svals,
                                                  const unsigned char* __restrict__ sidx,
                                                  const int* __restrict__ row_off,
                                                  const int* __restrict__ csr_src,
                                                  const float* __restrict__ dvin,
                                                  const float* __restrict__ bg,
                                                  float* __restrict__ out, int n) {
    __shared__ float acc[4][128];
    const int wv = threadIdx.x >> 6;
    const int lane = threadIdx.x & 63;
    const int node = blockIdx.x * 4 + wv;
    acc[wv][lane] = 0.f;
    acc[wv][lane + 64] = 0.f;
    if (node < n) {
        int s0 = row_off[node], s1 = row_off[node + 1];
        int sub = lane >> 3;           // 0..7: edge slot
        int j4 = (lane & 7) * 4;       // feature quad
        int e = s0 + sub;
        for (; e + 8 < s1; e += 16) {
            int sA = csr_src[e];
            int sB = csr_src[e + 8];
            float4 vA = *(const float4*)(svals + (size_t)sA * 32 + j4);
            float4 vB = *(const float4*)(svals + (size_t)sB * 32 + j4);
            uchar4 fA = *(const uchar4*)(sidx + (size_t)sA * 32 + j4);
            uchar4 fB = *(const uchar4*)(sidx + (size_t)sB * 32 + j4);
            atomicAdd(&acc[wv][fA.x], vA.x);
            atomicAdd(&acc[wv][fA.y], vA.y);
            atomicAdd(&acc[wv][fA.z], vA.z);
            atomicAdd(&acc[wv][fA.w], vA.w);
            atomicAdd(&acc[wv][fB.x], vB.x);
            atomicAdd(&acc[wv][fB.y], vB.y);
            atomicAdd(&acc[wv][fB.z], vB.z);
            atomicAdd(&acc[wv][fB.w], vB.w);
        }
        for (; e < s1; e += 8) {
            int sA = csr_src[e];
            float4 vA = *(const float4*)(svals + (size_t)sA * 32 + j4);
            uchar4 fA = *(const uchar4*)(sidx + (size_t)sA * 32 + j4);
            atomicAdd(&acc[wv][fA.x], vA.x);
            atomicAdd(&acc[wv][fA.y], vA.y);
            atomicAdd(&acc[wv][fA.z], vA.z);
            atomicAdd(&acc[wv][fA.w], vA.w);
        }
    }
    __syncthreads();
    if (node < n) {
        float dv = dvin[node];
        out[(size_t)node * 128 + lane] = acc[wv][lane] * dv + bg[lane];
        out[(size_t)node * 128 + lane + 64] = acc[wv][lane + 64] * dv + bg[lane + 64];
    }
}

// ---------------- GEMM [n,128] x [128,64] + bias -> d_out ----------------
__global__ __launch_bounds__(256) void gemm_out64(const float* __restrict__ A,
                                                  const float* __restrict__ W,
                                                  const float* __restrict__ bias,
                                                  float* __restrict__ out, int n) {
    __shared__ float As[64][32];
    __shared__ float Ws[32][64];
    const int tid = threadIdx.x;
    const int rbase = blockIdx.x * 64;
    const int cc = tid & 15;          // cols 4*cc
    const int r0 = (tid >> 4) * 4;    // 4 rows
    float acc[4][4];
#pragma unroll
    for (int i = 0; i < 4; ++i) { acc[i][0] = 0.f; acc[i][1] = 0.f; acc[i][2] = 0.f; acc[i][3] = 0.f; }

    for (int kc = 0; kc < 4; ++kc) {
        int lr = tid >> 3, c4 = (tid & 7) * 4;
#pragma unroll
        for (int p = 0; p < 2; ++p) {
            int row = lr + p * 32, gr = rbase + row;
            float4 v = make_float4(0.f, 0.f, 0.f, 0.f);
            if (gr < n) v = *(const float4*)(A + (size_t)gr * 128 + kc * 32 + c4);
            *(float4*)&As[row][c4] = v;
        }
        int wr = tid >> 4;  // 0..15
#pragma unroll
        for (int p = 0; p < 2; ++p) {
            int row = wr + p * 16;
            *(float4*)&Ws[row][cc * 4] = *(const float4*)(W + (size_t)(kc * 32 + row) * 64 + cc * 4);
        }
        __syncthreads();
#pragma unroll
        for (int k = 0; k < 32; k += 4) {
            float4 w0 = *(float4*)&Ws[k + 0][cc * 4];
            float4 w1 = *(float4*)&Ws[k + 1][cc * 4];
            float4 w2 = *(float4*)&Ws[k + 2][cc * 4];
            float4 w3 = *(float4*)&Ws[k + 3][cc * 4];
#pragma unroll
            for (int i = 0; i < 4; ++i) {
                float4 a = *(float4*)&As[r0 + i][k];
                acc[i][0] += a.x * w0.x + a.y * w1.x + a.z * w2.x + a.w * w3.x;
                acc[i][1] += a.x * w0.y + a.y * w1.y + a.z * w2.y + a.w * w3.y;
                acc[i][2] += a.x * w0.z + a.y * w1.z + a.z * w2.z + a.w * w3.z;
                acc[i][3] += a.x * w0.w + a.y * w1.w + a.z * w2.w + a.w * w3.w;
            }
        }
        __syncthreads();
    }
    float4 b4 = *(const float4*)(bias + cc * 4);
#pragma unroll
    for (int i = 0; i < 4; ++i) {
        int gr = rbase + r0 + i;
        if (gr < n) {
            float4 o = make_float4(acc[i][0] + b4.x, acc[i][1] + b4.y,
                                   acc[i][2] + b4.z, acc[i][3] + b4.w);
            *(float4*)(out + (size_t)gr * 64 + cc * 4) = o;
        }
    }
}

extern "C" void kernel_launch(void* const* d_in, const int* in_sizes, int n_in,
                              void* d_out, int out_size, void* d_ws, size_t ws_size,
                              hipStream_t stream) {
    const float* x     = (const float*)d_in[0];
    const int*   src   = (const int*)d_in[1];
    const int*   dst   = (const int*)d_in[2];
    const float* W_in  = (const float*)d_in[3];
    const float* b_in  = (const float*)d_in[4];
    const float* W1    = (const float*)d_in[5];
    const float* b1    = (const float*)d_in[6];
    const float* bg1   = (const float*)d_in[7];
    const float* W2    = (const float*)d_in[8];
    const float* b2    = (const float*)d_in[9];
    const float* bg2   = (const float*)d_in[10];
    const float* W_out = (const float*)d_in[11];
    const float* b_out = (const float*)d_in[12];
    float* out = (float*)d_out;

    char* p = (char*)d_ws;
    auto carve = [&](size_t bytes) {
        char* r = p;
        p += (bytes + 255) & ~(size_t)255;
        return r;
    };
    int*   cnt_out = (int*)carve((size_t)NN * 4);
    int*   cnt_in  = (int*)carve((size_t)NN * 4);
    float* dvout   = (float*)carve((size_t)NN * 4);
    float* dvin    = (float*)carve((size_t)NN * 4);
    int*   incl    = (int*)carve((size_t)NN * 4);
    int*   bsums   = (int*)carve(512 * 4);
    int*   boff    = (int*)carve(512 * 4);
    int*   row_off = (int*)carve((size_t)(NN + 1) * 4);
    int*   cursor  = (int*)carve((size_t)NN * 4);
    int*   csr_src = (int*)carve((size_t)EE * 4);
    float* hbuf    = (float*)carve((size_t)NN * HIDF * 4);
    float* svals   = (float*)carve((size_t)NN * KSEL * 4);
    unsigned char* sidx = (unsigned char*)carve((size_t)NN * KSEL);

    const int gN   = (NN + 255) / 256;   // 391
    const int gE   = (EE + 255) / 256;   // 6250
    const int gT   = (NN + 63) / 64;     // 1563 row tiles
    const int gAgg = (NN + 3) / 4;       // 25000

    hipMemsetAsync(cnt_out, 0, (size_t)NN * 4, stream);
    hipMemsetAsync(cnt_in, 0, (size_t)NN * 4, stream);
    hist_kernel<<<gE, 256, 0, stream>>>(src, dst, cnt_out, cnt_in, EE);
    scan_block<<<gN, 256, 0, stream>>>(cnt_in, incl, bsums, NN);
    scan_sums<<<1, 512, 0, stream>>>(bsums, boff, gN);
    finalize_offsets<<<gN, 256, 0, stream>>>(incl, boff, cnt_in, cnt_out, row_off, cursor,
                                             dvout, dvin, NN);
    csr_fill<<<gE, 256, 0, stream>>>(src, dst, cursor, csr_src, EE);

    gemm_relu<<<gT, 256, 0, stream>>>(x, W_in, b_in, hbuf, NN);

    gemm_maxk<<<gT, 256, 0, stream>>>(hbuf, W1, b1, dvout, svals, sidx, NN);
    agg_kernel<<<gAgg, 256, 0, stream>>>(svals, sidx, row_off, csr_src, dvin, bg1, hbuf, NN);

    gemm_maxk<<<gT, 256, 0, stream>>>(hbuf, W2, b2, dvout, svals, sidx, NN);
    agg_kernel<<<gAgg, 256, 0, stream>>>(svals, sidx, row_off, csr_src, dvin, bg2, hbuf, NN);

    gemm_out64<<<gT, 256, 0, stream>>>(hbuf, W_out, b_out, out, NN);
}

// Round 3
// 1318.073 us; speedup vs baseline: 1.1989x; 1.1989x over previous
//
#include <hip/hip_runtime.h>

#define NN   100000
#define EE   1600000
#define HIDF 128
#define OUTF 64
#define KSEL 32

static __device__ __forceinline__ unsigned int sortable_key(float f) {
    unsigned int u = __float_as_uint(f);
    return (u & 0x80000000u) ? ~u : (u | 0x80000000u);
}

// ---------------- degree histogram ----------------
__global__ __launch_bounds__(256) void hist_kernel(const int* __restrict__ src,
                                                   const int* __restrict__ dst,
                                                   int* __restrict__ cnt_out,
                                                   int* __restrict__ cnt_in, int e) {
    int i = blockIdx.x * 256 + threadIdx.x;
    if (i < e) {
        atomicAdd(&cnt_out[src[i]], 1);
        atomicAdd(&cnt_in[dst[i]], 1);
    }
}

// ---------------- prefix scan (3 kernels) ----------------
__global__ __launch_bounds__(256) void scan_block(const int* __restrict__ cnt,
                                                  int* __restrict__ incl,
                                                  int* __restrict__ bsums, int n) {
    __shared__ int s[256];
    int t = threadIdx.x;
    int i = blockIdx.x * 256 + t;
    int v = (i < n) ? cnt[i] : 0;
    s[t] = v;
    __syncthreads();
    for (int off = 1; off < 256; off <<= 1) {
        int x = (t >= off) ? s[t - off] : 0;
        __syncthreads();
        s[t] += x;
        __syncthreads();
    }
    if (i < n) incl[i] = s[t];
    if (t == 255) bsums[blockIdx.x] = s[255];
}

__global__ __launch_bounds__(512) void scan_sums(const int* __restrict__ bsums,
                                                 int* __restrict__ boff, int nb) {
    __shared__ int s[512];
    int t = threadIdx.x;
    int v = (t < nb) ? bsums[t] : 0;
    s[t] = v;
    __syncthreads();
    for (int off = 1; off < 512; off <<= 1) {
        int x = (t >= off) ? s[t - off] : 0;
        __syncthreads();
        s[t] += x;
        __syncthreads();
    }
    boff[t] = s[t] - v;  // exclusive
}

__global__ __launch_bounds__(256) void finalize_offsets(const int* __restrict__ incl,
                                                        const int* __restrict__ boff,
                                                        const int* __restrict__ cnt_in,
                                                        const int* __restrict__ cnt_out,
                                                        int* __restrict__ row_off,
                                                        int* __restrict__ cursor,
                                                        float* __restrict__ dvo,
                                                        float* __restrict__ dvi, int n) {
    int i = blockIdx.x * 256 + threadIdx.x;
    if (i < n) {
        int ci = cnt_in[i];
        int val = incl[i] + boff[i >> 8];
        row_off[i + 1] = val;
        cursor[i] = val - ci;
        if (i == 0) row_off[0] = 0;
        dvo[i] = rsqrtf((float)max(cnt_out[i], 1));
        dvi[i] = rsqrtf((float)max(ci, 1));
    }
}

__global__ __launch_bounds__(256) void csr_fill(const int* __restrict__ src,
                                                const int* __restrict__ dst,
                                                int* __restrict__ cursor,
                                                int* __restrict__ csr, int e) {
    int i = blockIdx.x * 256 + threadIdx.x;
    if (i < e) {
        int d = dst[i];
        int pos = atomicAdd(&cursor[d], 1);
        csr[pos] = src[i];
    }
}

// ---------------- GEMM [n,128] x [128,128] + bias + ReLU ----------------
// W staged in LDS (two 32KB halves, 2 barriers/block); A streamed from global
// (2 unique 16B lines per wave instr -> L1 broadcast). No barriers in k-loop.
__global__ __launch_bounds__(256, 4) void gemm_relu(const float* __restrict__ A,
                                                    const float* __restrict__ W,
                                                    const float* __restrict__ bias,
                                                    float* __restrict__ out, int n) {
    __shared__ float Ws[64][128];
    const int tid = threadIdx.x;
    const int rbase = blockIdx.x * 64;
    const int cc = tid & 31;
    const int r0 = (tid >> 5) * 8;
    const bool full = (rbase + 64) <= n;
    const float* a_base = A + (size_t)(rbase + r0) * 128;
    float acc[8][4];
#pragma unroll
    for (int i = 0; i < 8; ++i) { acc[i][0] = 0.f; acc[i][1] = 0.f; acc[i][2] = 0.f; acc[i][3] = 0.f; }

    for (int half = 0; half < 2; ++half) {
        const int kb = half * 64;
        if (half) __syncthreads();
#pragma unroll
        for (int q = 0; q < 8; ++q) {
            int f = q * 256 + tid;
            float4 v = *(const float4*)(W + (size_t)kb * 128 + (size_t)f * 4);
            *(float4*)&Ws[f >> 5][(f & 31) * 4] = v;
        }
        __syncthreads();
        if (full) {
            for (int kq = 0; kq < 16; ++kq) {
                int k = kq * 4;
                float4 w0 = *(float4*)&Ws[k + 0][cc * 4];
                float4 w1 = *(float4*)&Ws[k + 1][cc * 4];
                float4 w2 = *(float4*)&Ws[k + 2][cc * 4];
                float4 w3 = *(float4*)&Ws[k + 3][cc * 4];
#pragma unroll
                for (int i = 0; i < 8; ++i) {
                    float4 a = *(const float4*)(a_base + (size_t)i * 128 + kb + k);
                    acc[i][0] += a.x * w0.x + a.y * w1.x + a.z * w2.x + a.w * w3.x;
                    acc[i][1] += a.x * w0.y + a.y * w1.y + a.z * w2.y + a.w * w3.y;
                    acc[i][2] += a.x * w0.z + a.y * w1.z + a.z * w2.z + a.w * w3.z;
                    acc[i][3] += a.x * w0.w + a.y * w1.w + a.z * w2.w + a.w * w3.w;
                }
            }
        } else {
            for (int kq = 0; kq < 16; ++kq) {
                int k = kq * 4;
                float4 w0 = *(float4*)&Ws[k + 0][cc * 4];
                float4 w1 = *(float4*)&Ws[k + 1][cc * 4];
                float4 w2 = *(float4*)&Ws[k + 2][cc * 4];
                float4 w3 = *(float4*)&Ws[k + 3][cc * 4];
#pragma unroll
                for (int i = 0; i < 8; ++i) {
                    float4 a = make_float4(0.f, 0.f, 0.f, 0.f);
                    if (rbase + r0 + i < n) a = *(const float4*)(a_base + (size_t)i * 128 + kb + k);
                    acc[i][0] += a.x * w0.x + a.y * w1.x + a.z * w2.x + a.w * w3.x;
                    acc[i][1] += a.x * w0.y + a.y * w1.y + a.z * w2.y + a.w * w3.y;
                    acc[i][2] += a.x * w0.z + a.y * w1.z + a.z * w2.z + a.w * w3.z;
                    acc[i][3] += a.x * w0.w + a.y * w1.w + a.z * w2.w + a.w * w3.w;
                }
            }
        }
    }
    float4 b4 = *(const float4*)(bias + cc * 4);
#pragma unroll
    for (int i = 0; i < 8; ++i) {
        int gr = rbase + r0 + i;
        if (gr < n) {
            float4 o = make_float4(fmaxf(acc[i][0] + b4.x, 0.f), fmaxf(acc[i][1] + b4.y, 0.f),
                                   fmaxf(acc[i][2] + b4.z, 0.f), fmaxf(acc[i][3] + b4.w, 0.f));
            *(float4*)(out + (size_t)gr * 128 + cc * 4) = o;
        }
    }
}

// ---------------- GEMM + bias + MaxK(top-32) fused in-register ----------------
// A must be padded to >= 64-row multiple (reads unguarded). Select runs on the
// acc registers: wave holds rows rbase+16w..+15 (lower half lanes: rows i,
// upper half: rows i+8), 4 cols/lane (cc*4..+3). Radix ballot select, two rows
// per chain step, exact lowest-feature-index tie break (JAX top_k semantics).
__global__ __launch_bounds__(256, 4) void gemm_maxk(const float* __restrict__ A,
                                                    const float* __restrict__ W,
                                                    const float* __restrict__ bias,
                                                    const float* __restrict__ dvout,
                                                    float* __restrict__ svals,
                                                    unsigned char* __restrict__ sidx, int n) {
    __shared__ float Ws[64][128];
    const int tid = threadIdx.x;
    const int rbase = blockIdx.x * 64;
    const int cc = tid & 31;
    const int r0 = (tid >> 5) * 8;
    const float* a_base = A + (size_t)(rbase + r0) * 128;
    float acc[8][4];
#pragma unroll
    for (int i = 0; i < 8; ++i) { acc[i][0] = 0.f; acc[i][1] = 0.f; acc[i][2] = 0.f; acc[i][3] = 0.f; }

    for (int half = 0; half < 2; ++half) {
        const int kb = half * 64;
        if (half) __syncthreads();
#pragma unroll
        for (int q = 0; q < 8; ++q) {
            int f = q * 256 + tid;
            float4 v = *(const float4*)(W + (size_t)kb * 128 + (size_t)f * 4);
            *(float4*)&Ws[f >> 5][(f & 31) * 4] = v;
        }
        __syncthreads();
        for (int kq = 0; kq < 16; ++kq) {
            int k = kq * 4;
            float4 w0 = *(float4*)&Ws[k + 0][cc * 4];
            float4 w1 = *(float4*)&Ws[k + 1][cc * 4];
            float4 w2 = *(float4*)&Ws[k + 2][cc * 4];
            float4 w3 = *(float4*)&Ws[k + 3][cc * 4];
#pragma unroll
            for (int i = 0; i < 8; ++i) {
                float4 a = *(const float4*)(a_base + (size_t)i * 128 + kb + k);
                acc[i][0] += a.x * w0.x + a.y * w1.x + a.z * w2.x + a.w * w3.x;
                acc[i][1] += a.x * w0.y + a.y * w1.y + a.z * w2.y + a.w * w3.y;
                acc[i][2] += a.x * w0.z + a.y * w1.z + a.z * w2.z + a.w * w3.z;
                acc[i][3] += a.x * w0.w + a.y * w1.w + a.z * w2.w + a.w * w3.w;
            }
        }
    }

    // ---- fused MaxK select ----
    const int lane = tid & 63;
    const int wvi = tid >> 6;
    const bool up = lane >= 32;
    const unsigned lt32 = (1u << (lane & 31)) - 1u;
    float4 b4 = *(const float4*)(bias + cc * 4);

#pragma unroll 1
    for (int i = 0; i < 8; ++i) {
        int row = rbase + 16 * wvi + i + (up ? 8 : 0);
        float v0 = acc[i][0] + b4.x;
        float v1 = acc[i][1] + b4.y;
        float v2 = acc[i][2] + b4.z;
        float v3 = acc[i][3] + b4.w;
        unsigned k0 = sortable_key(v0), k1 = sortable_key(v1);
        unsigned k2 = sortable_key(v2), k3 = sortable_key(v3);
        unsigned prefL = 0u, prefU = 0u;
        for (int bit = 31; bit >= 0; --bit) {
            unsigned cL = prefL | (1u << bit);
            unsigned cU = prefU | (1u << bit);
            unsigned myc = up ? cU : cL;
            unsigned long long b0 = __ballot(k0 >= myc);
            unsigned long long b1 = __ballot(k1 >= myc);
            unsigned long long b2 = __ballot(k2 >= myc);
            unsigned long long b3 = __ballot(k3 >= myc);
            int cntL = __popc((unsigned)b0) + __popc((unsigned)b1) +
                       __popc((unsigned)b2) + __popc((unsigned)b3);
            int cntU = __popc((unsigned)(b0 >> 32)) + __popc((unsigned)(b1 >> 32)) +
                       __popc((unsigned)(b2 >> 32)) + __popc((unsigned)(b3 >> 32));
            prefL = (cntL >= KSEL) ? cL : prefL;
            prefU = (cntU >= KSEL) ? cU : prefU;
        }
        unsigned myp = up ? prefU : prefL;
        unsigned long long g0 = __ballot(k0 > myp), g1 = __ballot(k1 > myp);
        unsigned long long g2 = __ballot(k2 > myp), g3 = __ballot(k3 > myp);
        unsigned long long e0 = __ballot(k0 == myp), e1 = __ballot(k1 == myp);
        unsigned long long e2 = __ballot(k2 == myp), e3 = __ballot(k3 == myp);
        unsigned gh0 = up ? (unsigned)(g0 >> 32) : (unsigned)g0;
        unsigned gh1 = up ? (unsigned)(g1 >> 32) : (unsigned)g1;
        unsigned gh2 = up ? (unsigned)(g2 >> 32) : (unsigned)g2;
        unsigned gh3 = up ? (unsigned)(g3 >> 32) : (unsigned)g3;
        unsigned eh0 = up ? (unsigned)(e0 >> 32) : (unsigned)e0;
        unsigned eh1 = up ? (unsigned)(e1 >> 32) : (unsigned)e1;
        unsigned eh2 = up ? (unsigned)(e2 >> 32) : (unsigned)e2;
        unsigned eh3 = up ? (unsigned)(e3 >> 32) : (unsigned)e3;
        int m = __popc(gh0) + __popc(gh1) + __popc(gh2) + __popc(gh3);
        int need = KSEL - m;
        int gpos = __popc(gh0 & lt32) + __popc(gh1 & lt32) + __popc(gh2 & lt32) + __popc(gh3 & lt32);
        int epos = __popc(eh0 & lt32) + __popc(eh1 & lt32) + __popc(eh2 & lt32) + __popc(eh3 & lt32);
        bool ok = row < n;
        float ds = dvout[row];
        size_t base = (size_t)row * 32;
        unsigned cbit = (unsigned)(lane & 31);
        // j = 0
        {
            int slot = -1;
            if (k0 > myp) slot = gpos;
            else if (k0 == myp && epos < need) slot = m + epos;
            if (slot >= 0 && ok) { svals[base + slot] = v0 * ds; sidx[base + slot] = (unsigned char)(cc * 4 + 0); }
            gpos += (gh0 >> cbit) & 1u;
            epos += (eh0 >> cbit) & 1u;
        }
        // j = 1
        {
            int slot = -1;
            if (k1 > myp) slot = gpos;
            else if (k1 == myp && epos < need) slot = m + epos;
            if (slot >= 0 && ok) { svals[base + slot] = v1 * ds; sidx[base + slot] = (unsigned char)(cc * 4 + 1); }
            gpos += (gh1 >> cbit) & 1u;
            epos += (eh1 >> cbit) & 1u;
        }
        // j = 2
        {
            int slot = -1;
            if (k2 > myp) slot = gpos;
            else if (k2 == myp && epos < need) slot = m + epos;
            if (slot >= 0 && ok) { svals[base + slot] = v2 * ds; sidx[base + slot] = (unsigned char)(cc * 4 + 2); }
            gpos += (gh2 >> cbit) & 1u;
            epos += (eh2 >> cbit) & 1u;
        }
        // j = 3
        {
            int slot = -1;
            if (k3 > myp) slot = gpos;
            else if (k3 == myp && epos < need) slot = m + epos;
            if (slot >= 0 && ok) { svals[base + slot] = v3 * ds; sidx[base + slot] = (unsigned char)(cc * 4 + 3); }
        }
    }
}

// ---------------- CSR aggregation: one wave per dst node, LDS accumulator ----------------
__global__ __launch_bounds__(256) void agg_kernel(const float* __restrict__ svals,
                                                  const unsigned char* __restrict__ sidx,
                                                  const int* __restrict__ row_off,
                                                  const int* __restrict__ csr_src,
                                                  const float* __restrict__ dvin,
                                                  const float* __restrict__ bg,
                                                  float* __restrict__ out, int n) {
    __shared__ float acc[4][128];
    const int wv = threadIdx.x >> 6;
    const int lane = threadIdx.x & 63;
    const int node = blockIdx.x * 4 + wv;
    acc[wv][lane] = 0.f;
    acc[wv][lane + 64] = 0.f;
    if (node < n) {
        int s0 = row_off[node], s1 = row_off[node + 1];
        int sub = lane >> 3;           // 0..7: edge slot
        int j4 = (lane & 7) * 4;       // feature quad
        int e = s0 + sub;
        for (; e + 8 < s1; e += 16) {
            int sA = csr_src[e];
            int sB = csr_src[e + 8];
            float4 vA = *(const float4*)(svals + (size_t)sA * 32 + j4);
            float4 vB = *(const float4*)(svals + (size_t)sB * 32 + j4);
            uchar4 fA = *(const uchar4*)(sidx + (size_t)sA * 32 + j4);
            uchar4 fB = *(const uchar4*)(sidx + (size_t)sB * 32 + j4);
            atomicAdd(&acc[wv][fA.x], vA.x);
            atomicAdd(&acc[wv][fA.y], vA.y);
            atomicAdd(&acc[wv][fA.z], vA.z);
            atomicAdd(&acc[wv][fA.w], vA.w);
            atomicAdd(&acc[wv][fB.x], vB.x);
            atomicAdd(&acc[wv][fB.y], vB.y);
            atomicAdd(&acc[wv][fB.z], vB.z);
            atomicAdd(&acc[wv][fB.w], vB.w);
        }
        for (; e < s1; e += 8) {
            int sA = csr_src[e];
            float4 vA = *(const float4*)(svals + (size_t)sA * 32 + j4);
            uchar4 fA = *(const uchar4*)(sidx + (size_t)sA * 32 + j4);
            atomicAdd(&acc[wv][fA.x], vA.x);
            atomicAdd(&acc[wv][fA.y], vA.y);
            atomicAdd(&acc[wv][fA.z], vA.z);
            atomicAdd(&acc[wv][fA.w], vA.w);
        }
    }
    __syncthreads();
    if (node < n) {
        float dv = dvin[node];
        out[(size_t)node * 128 + lane] = acc[wv][lane] * dv + bg[lane];
        out[(size_t)node * 128 + lane + 64] = acc[wv][lane + 64] * dv + bg[lane + 64];
    }
}

// ---------------- GEMM [n,128] x [128,64] + bias -> d_out ----------------
// Full W (32KB) staged once, single barrier; A streamed from global (padded).
__global__ __launch_bounds__(256, 4) void gemm_out64(const float* __restrict__ A,
                                                     const float* __restrict__ W,
                                                     const float* __restrict__ bias,
                                                     float* __restrict__ out, int n) {
    __shared__ float Ws[128][64];
    const int tid = threadIdx.x;
    const int rbase = blockIdx.x * 64;
    const int cc = tid & 15;
    const int r0 = (tid >> 4) * 4;
    const float* a_base = A + (size_t)(rbase + r0) * 128;
    float acc[4][4];
#pragma unroll
    for (int i = 0; i < 4; ++i) { acc[i][0] = 0.f; acc[i][1] = 0.f; acc[i][2] = 0.f; acc[i][3] = 0.f; }

#pragma unroll
    for (int q = 0; q < 8; ++q) {
        int f = q * 256 + tid;
        float4 v = *(const float4*)(W + (size_t)f * 4);
        *(float4*)&Ws[f >> 4][(f & 15) * 4] = v;
    }
    __syncthreads();
    for (int kq = 0; kq < 32; ++kq) {
        int k = kq * 4;
        float4 w0 = *(float4*)&Ws[k + 0][cc * 4];
        float4 w1 = *(float4*)&Ws[k + 1][cc * 4];
        float4 w2 = *(float4*)&Ws[k + 2][cc * 4];
        float4 w3 = *(float4*)&Ws[k + 3][cc * 4];
#pragma unroll
        for (int i = 0; i < 4; ++i) {
            float4 a = *(const float4*)(a_base + (size_t)i * 128 + k);
            acc[i][0] += a.x * w0.x + a.y * w1.x + a.z * w2.x + a.w * w3.x;
            acc[i][1] += a.x * w0.y + a.y * w1.y + a.z * w2.y + a.w * w3.y;
            acc[i][2] += a.x * w0.z + a.y * w1.z + a.z * w2.z + a.w * w3.z;
            acc[i][3] += a.x * w0.w + a.y * w1.w + a.z * w2.w + a.w * w3.w;
        }
    }
    float4 b4 = *(const float4*)(bias + cc * 4);
#pragma unroll
    for (int i = 0; i < 4; ++i) {
        int gr = rbase + r0 + i;
        if (gr < n) {
            float4 o = make_float4(acc[i][0] + b4.x, acc[i][1] + b4.y,
                                   acc[i][2] + b4.z, acc[i][3] + b4.w);
            *(float4*)(out + (size_t)gr * 64 + cc * 4) = o;
        }
    }
}

extern "C" void kernel_launch(void* const* d_in, const int* in_sizes, int n_in,
                              void* d_out, int out_size, void* d_ws, size_t ws_size,
                              hipStream_t stream) {
    const float* x     = (const float*)d_in[0];
    const int*   src   = (const int*)d_in[1];
    const int*   dst   = (const int*)d_in[2];
    const float* W_in  = (const float*)d_in[3];
    const float* b_in  = (const float*)d_in[4];
    const float* W1    = (const float*)d_in[5];
    const float* b1    = (const float*)d_in[6];
    const float* bg1   = (const float*)d_in[7];
    const float* W2    = (const float*)d_in[8];
    const float* b2    = (const float*)d_in[9];
    const float* bg2   = (const float*)d_in[10];
    const float* W_out = (const float*)d_in[11];
    const float* b_out = (const float*)d_in[12];
    float* out = (float*)d_out;

    char* p = (char*)d_ws;
    auto carve = [&](size_t bytes) {
        char* r = p;
        p += (bytes + 255) & ~(size_t)255;
        return r;
    };
    int*   cnt_out = (int*)carve((size_t)NN * 4);
    int*   cnt_in  = (int*)carve((size_t)NN * 4);
    float* dvout   = (float*)carve((size_t)(NN + 128) * 4);  // padded: gemm_maxk reads OOB rows
    float* dvin    = (float*)carve((size_t)NN * 4);
    int*   incl    = (int*)carve((size_t)NN * 4);
    int*   bsums   = (int*)carve(512 * 4);
    int*   boff    = (int*)carve(512 * 4);
    int*   row_off = (int*)carve((size_t)(NN + 1) * 4);
    int*   cursor  = (int*)carve((size_t)NN * 4);
    int*   csr_src = (int*)carve((size_t)EE * 4);
    float* hbuf    = (float*)carve((size_t)(NN + 128) * HIDF * 4);  // padded rows
    float* svals   = (float*)carve((size_t)NN * KSEL * 4);
    unsigned char* sidx = (unsigned char*)carve((size_t)NN * KSEL);

    const int gN   = (NN + 255) / 256;   // 391
    const int gE   = (EE + 255) / 256;   // 6250
    const int gT   = (NN + 63) / 64;     // 1563 row tiles
    const int gAgg = (NN + 3) / 4;       // 25000

    hipMemsetAsync(cnt_out, 0, (size_t)NN * 4, stream);
    hipMemsetAsync(cnt_in, 0, (size_t)NN * 4, stream);
    hist_kernel<<<gE, 256, 0, stream>>>(src, dst, cnt_out, cnt_in, EE);
    scan_block<<<gN, 256, 0, stream>>>(cnt_in, incl, bsums, NN);
    scan_sums<<<1, 512, 0, stream>>>(bsums, boff, gN);
    finalize_offsets<<<gN, 256, 0, stream>>>(incl, boff, cnt_in, cnt_out, row_off, cursor,
                                             dvout, dvin, NN);
    csr_fill<<<gE, 256, 0, stream>>>(src, dst, cursor, csr_src, EE);

    gemm_relu<<<gT, 256, 0, stream>>>(x, W_in, b_in, hbuf, NN);

    gemm_maxk<<<gT, 256, 0, stream>>>(hbuf, W1, b1, dvout, svals, sidx, NN);
    agg_kernel<<<gAgg, 256, 0, stream>>>(svals, sidx, row_off, csr_src, dvin, bg1, hbuf, NN);

    gemm_maxk<<<gT, 256, 0, stream>>>(hbuf, W2, b2, dvout, svals, sidx, NN);
    agg_kernel<<<gAgg, 256, 0, stream>>>(svals, sidx, row_off, csr_src, dvin, bg2, hbuf, NN);

    gemm_out64<<<gT, 256, 0, stream>>>(hbuf, W_out, b_out, out, NN);
}

// Round 4
// 1298.021 us; speedup vs baseline: 1.2174x; 1.0154x over previous
//
#include <hip/hip_runtime.h>

#define NN   100000
#define EE   1600000
#define HIDF 128
#define OUTF 64
#define KSEL 32

static __device__ __forceinline__ unsigned int sortable_key(float f) {
    unsigned int u = __float_as_uint(f);
    return (u & 0x80000000u) ? ~u : (u | 0x80000000u);
}

// ---------------- degree histogram ----------------
__global__ __launch_bounds__(256) void hist_kernel(const int* __restrict__ src,
                                                   const int* __restrict__ dst,
                                                   int* __restrict__ cnt_out,
                                                   int* __restrict__ cnt_in, int e) {
    int i = blockIdx.x * 256 + threadIdx.x;
    if (i < e) {
        atomicAdd(&cnt_out[src[i]], 1);
        atomicAdd(&cnt_in[dst[i]], 1);
    }
}

// ---------------- prefix scan (3 kernels) ----------------
__global__ __launch_bounds__(256) void scan_block(const int* __restrict__ cnt,
                                                  int* __restrict__ incl,
                                                  int* __restrict__ bsums, int n) {
    __shared__ int s[256];
    int t = threadIdx.x;
    int i = blockIdx.x * 256 + t;
    int v = (i < n) ? cnt[i] : 0;
    s[t] = v;
    __syncthreads();
    for (int off = 1; off < 256; off <<= 1) {
        int x = (t >= off) ? s[t - off] : 0;
        __syncthreads();
        s[t] += x;
        __syncthreads();
    }
    if (i < n) incl[i] = s[t];
    if (t == 255) bsums[blockIdx.x] = s[255];
}

__global__ __launch_bounds__(512) void scan_sums(const int* __restrict__ bsums,
                                                 int* __restrict__ boff, int nb) {
    __shared__ int s[512];
    int t = threadIdx.x;
    int v = (t < nb) ? bsums[t] : 0;
    s[t] = v;
    __syncthreads();
    for (int off = 1; off < 512; off <<= 1) {
        int x = (t >= off) ? s[t - off] : 0;
        __syncthreads();
        s[t] += x;
        __syncthreads();
    }
    boff[t] = s[t] - v;  // exclusive
}

__global__ __launch_bounds__(256) void finalize_offsets(const int* __restrict__ incl,
                                                        const int* __restrict__ boff,
                                                        const int* __restrict__ cnt_in,
                                                        const int* __restrict__ cnt_out,
                                                        int* __restrict__ row_off,
                                                        int* __restrict__ cursor,
                                                        float* __restrict__ dvo,
                                                        float* __restrict__ dvi, int n) {
    int i = blockIdx.x * 256 + threadIdx.x;
    if (i < n) {
        int ci = cnt_in[i];
        int val = incl[i] + boff[i >> 8];
        row_off[i + 1] = val;
        cursor[i] = val - ci;
        if (i == 0) row_off[0] = 0;
        dvo[i] = rsqrtf((float)max(cnt_out[i], 1));
        dvi[i] = rsqrtf((float)max(ci, 1));
    }
}

__global__ __launch_bounds__(256) void csr_fill(const int* __restrict__ src,
                                                const int* __restrict__ dst,
                                                int* __restrict__ cursor,
                                                int* __restrict__ csr, int e) {
    int i = blockIdx.x * 256 + threadIdx.x;
    if (i < e) {
        int d = dst[i];
        int pos = atomicAdd(&cursor[d], 1);
        csr[pos] = src[i];
    }
}

// ---------------- GEMM [n,128] x [128,128] + bias + ReLU ----------------
__global__ __launch_bounds__(256, 4) void gemm_relu(const float* __restrict__ A,
                                                    const float* __restrict__ W,
                                                    const float* __restrict__ bias,
                                                    float* __restrict__ out, int n) {
    __shared__ float Ws[64][128];
    const int tid = threadIdx.x;
    const int rbase = blockIdx.x * 64;
    const int cc = tid & 31;
    const int r0 = (tid >> 5) * 8;
    const bool full = (rbase + 64) <= n;
    const float* a_base = A + (size_t)(rbase + r0) * 128;
    float acc[8][4];
#pragma unroll
    for (int i = 0; i < 8; ++i) { acc[i][0] = 0.f; acc[i][1] = 0.f; acc[i][2] = 0.f; acc[i][3] = 0.f; }

    for (int half = 0; half < 2; ++half) {
        const int kb = half * 64;
        if (half) __syncthreads();
#pragma unroll
        for (int q = 0; q < 8; ++q) {
            int f = q * 256 + tid;
            float4 v = *(const float4*)(W + (size_t)kb * 128 + (size_t)f * 4);
            *(float4*)&Ws[f >> 5][(f & 31) * 4] = v;
        }
        __syncthreads();
        if (full) {
            for (int kq = 0; kq < 16; ++kq) {
                int k = kq * 4;
                float4 w0 = *(float4*)&Ws[k + 0][cc * 4];
                float4 w1 = *(float4*)&Ws[k + 1][cc * 4];
                float4 w2 = *(float4*)&Ws[k + 2][cc * 4];
                float4 w3 = *(float4*)&Ws[k + 3][cc * 4];
#pragma unroll
                for (int i = 0; i < 8; ++i) {
                    float4 a = *(const float4*)(a_base + (size_t)i * 128 + kb + k);
                    acc[i][0] += a.x * w0.x + a.y * w1.x + a.z * w2.x + a.w * w3.x;
                    acc[i][1] += a.x * w0.y + a.y * w1.y + a.z * w2.y + a.w * w3.y;
                    acc[i][2] += a.x * w0.z + a.y * w1.z + a.z * w2.z + a.w * w3.z;
                    acc[i][3] += a.x * w0.w + a.y * w1.w + a.z * w2.w + a.w * w3.w;
                }
            }
        } else {
            for (int kq = 0; kq < 16; ++kq) {
                int k = kq * 4;
                float4 w0 = *(float4*)&Ws[k + 0][cc * 4];
                float4 w1 = *(float4*)&Ws[k + 1][cc * 4];
                float4 w2 = *(float4*)&Ws[k + 2][cc * 4];
                float4 w3 = *(float4*)&Ws[k + 3][cc * 4];
#pragma unroll
                for (int i = 0; i < 8; ++i) {
                    float4 a = make_float4(0.f, 0.f, 0.f, 0.f);
                    if (rbase + r0 + i < n) a = *(const float4*)(a_base + (size_t)i * 128 + kb + k);
                    acc[i][0] += a.x * w0.x + a.y * w1.x + a.z * w2.x + a.w * w3.x;
                    acc[i][1] += a.x * w0.y + a.y * w1.y + a.z * w2.y + a.w * w3.y;
                    acc[i][2] += a.x * w0.z + a.y * w1.z + a.z * w2.z + a.w * w3.z;
                    acc[i][3] += a.x * w0.w + a.y * w1.w + a.z * w2.w + a.w * w3.w;
                }
            }
        }
    }
    float4 b4 = *(const float4*)(bias + cc * 4);
#pragma unroll
    for (int i = 0; i < 8; ++i) {
        int gr = rbase + r0 + i;
        if (gr < n) {
            float4 o = make_float4(fmaxf(acc[i][0] + b4.x, 0.f), fmaxf(acc[i][1] + b4.y, 0.f),
                                   fmaxf(acc[i][2] + b4.z, 0.f), fmaxf(acc[i][3] + b4.w, 0.f));
            *(float4*)(out + (size_t)gr * 128 + cc * 4) = o;
        }
    }
}

// ---------------- GEMM + bias + MaxK(top-32) fused in-register ----------------
// Sparse record: 32 fp32 values per node, feature index stuffed into the low
// 7 mantissa bits of each value (rel. perturbation <= 1.5e-5). One 128-B
// aligned record -> 2 cache lines per edge in agg (was 3 with separate sidx).
// Radix select truncated to bits 31..8: ties within a 256-ulp bucket are
// broken by feature order; any mis-pick perturbs the kept value <= 3e-5 rel.
__global__ __launch_bounds__(256, 4) void gemm_maxk(const float* __restrict__ A,
                                                    const float* __restrict__ W,
                                                    const float* __restrict__ bias,
                                                    const float* __restrict__ dvout,
                                                    float* __restrict__ svals, int n) {
    __shared__ float Ws[64][128];
    const int tid = threadIdx.x;
    const int rbase = blockIdx.x * 64;
    const int cc = tid & 31;
    const int r0 = (tid >> 5) * 8;
    const float* a_base = A + (size_t)(rbase + r0) * 128;
    float acc[8][4];
#pragma unroll
    for (int i = 0; i < 8; ++i) { acc[i][0] = 0.f; acc[i][1] = 0.f; acc[i][2] = 0.f; acc[i][3] = 0.f; }

    for (int half = 0; half < 2; ++half) {
        const int kb = half * 64;
        if (half) __syncthreads();
#pragma unroll
        for (int q = 0; q < 8; ++q) {
            int f = q * 256 + tid;
            float4 v = *(const float4*)(W + (size_t)kb * 128 + (size_t)f * 4);
            *(float4*)&Ws[f >> 5][(f & 31) * 4] = v;
        }
        __syncthreads();
        for (int kq = 0; kq < 16; ++kq) {
            int k = kq * 4;
            float4 w0 = *(float4*)&Ws[k + 0][cc * 4];
            float4 w1 = *(float4*)&Ws[k + 1][cc * 4];
            float4 w2 = *(float4*)&Ws[k + 2][cc * 4];
            float4 w3 = *(float4*)&Ws[k + 3][cc * 4];
#pragma unroll
            for (int i = 0; i < 8; ++i) {
                float4 a = *(const float4*)(a_base + (size_t)i * 128 + kb + k);
                acc[i][0] += a.x * w0.x + a.y * w1.x + a.z * w2.x + a.w * w3.x;
                acc[i][1] += a.x * w0.y + a.y * w1.y + a.z * w2.y + a.w * w3.y;
                acc[i][2] += a.x * w0.z + a.y * w1.z + a.z * w2.z + a.w * w3.z;
                acc[i][3] += a.x * w0.w + a.y * w1.w + a.z * w2.w + a.w * w3.w;
            }
        }
    }

    // ---- fused MaxK select ----
    const int lane = tid & 63;
    const int wvi = tid >> 6;
    const bool up = lane >= 32;
    const unsigned lt32 = (1u << (lane & 31)) - 1u;
    float4 b4 = *(const float4*)(bias + cc * 4);

#pragma unroll 1
    for (int i = 0; i < 8; ++i) {
        int row = rbase + 16 * wvi + i + (up ? 8 : 0);
        float v0 = acc[i][0] + b4.x;
        float v1 = acc[i][1] + b4.y;
        float v2 = acc[i][2] + b4.z;
        float v3 = acc[i][3] + b4.w;
        unsigned k0 = sortable_key(v0), k1 = sortable_key(v1);
        unsigned k2 = sortable_key(v2), k3 = sortable_key(v3);
        unsigned prefL = 0u, prefU = 0u;
        for (int bit = 31; bit >= 8; --bit) {
            unsigned cL = prefL | (1u << bit);
            unsigned cU = prefU | (1u << bit);
            unsigned myc = up ? cU : cL;
            unsigned long long b0 = __ballot(k0 >= myc);
            unsigned long long b1 = __ballot(k1 >= myc);
            unsigned long long b2 = __ballot(k2 >= myc);
            unsigned long long b3 = __ballot(k3 >= myc);
            int cntL = __popc((unsigned)b0) + __popc((unsigned)b1) +
                       __popc((unsigned)b2) + __popc((unsigned)b3);
            int cntU = __popc((unsigned)(b0 >> 32)) + __popc((unsigned)(b1 >> 32)) +
                       __popc((unsigned)(b2 >> 32)) + __popc((unsigned)(b3 >> 32));
            prefL = (cntL >= KSEL) ? cL : prefL;
            prefU = (cntU >= KSEL) ? cU : prefU;
        }
        unsigned myp = up ? prefU : prefL;
        unsigned kb0 = k0 & 0xFFFFFF00u, kb1 = k1 & 0xFFFFFF00u;
        unsigned kb2 = k2 & 0xFFFFFF00u, kb3 = k3 & 0xFFFFFF00u;
        unsigned long long g0 = __ballot(kb0 > myp), g1 = __ballot(kb1 > myp);
        unsigned long long g2 = __ballot(kb2 > myp), g3 = __ballot(kb3 > myp);
        unsigned long long e0 = __ballot(kb0 == myp), e1 = __ballot(kb1 == myp);
        unsigned long long e2 = __ballot(kb2 == myp), e3 = __ballot(kb3 == myp);
        unsigned gh0 = up ? (unsigned)(g0 >> 32) : (unsigned)g0;
        unsigned gh1 = up ? (unsigned)(g1 >> 32) : (unsigned)g1;
        unsigned gh2 = up ? (unsigned)(g2 >> 32) : (unsigned)g2;
        unsigned gh3 = up ? (unsigned)(g3 >> 32) : (unsigned)g3;
        unsigned eh0 = up ? (unsigned)(e0 >> 32) : (unsigned)e0;
        unsigned eh1 = up ? (unsigned)(e1 >> 32) : (unsigned)e1;
        unsigned eh2 = up ? (unsigned)(e2 >> 32) : (unsigned)e2;
        unsigned eh3 = up ? (unsigned)(e3 >> 32) : (unsigned)e3;
        int m = __popc(gh0) + __popc(gh1) + __popc(gh2) + __popc(gh3);
        int need = KSEL - m;
        int gpos = __popc(gh0 & lt32) + __popc(gh1 & lt32) + __popc(gh2 & lt32) + __popc(gh3 & lt32);
        int epos = __popc(eh0 & lt32) + __popc(eh1 & lt32) + __popc(eh2 & lt32) + __popc(eh3 & lt32);
        bool ok = row < n;
        float ds = dvout[row];
        size_t base = (size_t)row * 32;
        unsigned cbit = (unsigned)(lane & 31);
        // stuff feature idx into low 7 mantissa bits of val*ds
        // j = 0
        {
            int slot = -1;
            if (kb0 > myp) slot = gpos;
            else if (kb0 == myp && epos < need) slot = m + epos;
            if (slot >= 0 && ok) {
                unsigned u = (__float_as_uint(v0 * ds) & 0xFFFFFF80u) | (unsigned)(cc * 4 + 0);
                svals[base + slot] = __uint_as_float(u);
            }
            gpos += (gh0 >> cbit) & 1u;
            epos += (eh0 >> cbit) & 1u;
        }
        // j = 1
        {
            int slot = -1;
            if (kb1 > myp) slot = gpos;
            else if (kb1 == myp && epos < need) slot = m + epos;
            if (slot >= 0 && ok) {
                unsigned u = (__float_as_uint(v1 * ds) & 0xFFFFFF80u) | (unsigned)(cc * 4 + 1);
                svals[base + slot] = __uint_as_float(u);
            }
            gpos += (gh1 >> cbit) & 1u;
            epos += (eh1 >> cbit) & 1u;
        }
        // j = 2
        {
            int slot = -1;
            if (kb2 > myp) slot = gpos;
            else if (kb2 == myp && epos < need) slot = m + epos;
            if (slot >= 0 && ok) {
                unsigned u = (__float_as_uint(v2 * ds) & 0xFFFFFF80u) | (unsigned)(cc * 4 + 2);
                svals[base + slot] = __uint_as_float(u);
            }
            gpos += (gh2 >> cbit) & 1u;
            epos += (eh2 >> cbit) & 1u;
        }
        // j = 3
        {
            int slot = -1;
            if (kb3 > myp) slot = gpos;
            else if (kb3 == myp && epos < need) slot = m + epos;
            if (slot >= 0 && ok) {
                unsigned u = (__float_as_uint(v3 * ds) & 0xFFFFFF80u) | (unsigned)(cc * 4 + 3);
                svals[base + slot] = __uint_as_float(u);
            }
        }
    }
}

// ---------------- CSR aggregation: one wave per dst node, LDS accumulator ----------------
// Feature idx lives in the low 7 mantissa bits of each value: one 128-B
// record (2 lines) per edge instead of 3.
__global__ __launch_bounds__(256) void agg_kernel(const float* __restrict__ svals,
                                                  const int* __restrict__ row_off,
                                                  const int* __restrict__ csr_src,
                                                  const float* __restrict__ dvin,
                                                  const float* __restrict__ bg,
                                                  float* __restrict__ out, int n) {
    __shared__ float acc[4][128];
    const int wv = threadIdx.x >> 6;
    const int lane = threadIdx.x & 63;
    const int node = blockIdx.x * 4 + wv;
    acc[wv][lane] = 0.f;
    acc[wv][lane + 64] = 0.f;
    if (node < n) {
        int s0 = row_off[node], s1 = row_off[node + 1];
        int sub = lane >> 3;           // 0..7: edge slot
        int j4 = (lane & 7) * 4;       // value quad
        int e = s0 + sub;
        for (; e + 8 < s1; e += 16) {
            int sA = csr_src[e];
            int sB = csr_src[e + 8];
            float4 vA = *(const float4*)(svals + (size_t)sA * 32 + j4);
            float4 vB = *(const float4*)(svals + (size_t)sB * 32 + j4);
            atomicAdd(&acc[wv][__float_as_uint(vA.x) & 127u], vA.x);
            atomicAdd(&acc[wv][__float_as_uint(vA.y) & 127u], vA.y);
            atomicAdd(&acc[wv][__float_as_uint(vA.z) & 127u], vA.z);
            atomicAdd(&acc[wv][__float_as_uint(vA.w) & 127u], vA.w);
            atomicAdd(&acc[wv][__float_as_uint(vB.x) & 127u], vB.x);
            atomicAdd(&acc[wv][__float_as_uint(vB.y) & 127u], vB.y);
            atomicAdd(&acc[wv][__float_as_uint(vB.z) & 127u], vB.z);
            atomicAdd(&acc[wv][__float_as_uint(vB.w) & 127u], vB.w);
        }
        for (; e < s1; e += 8) {
            int sA = csr_src[e];
            float4 vA = *(const float4*)(svals + (size_t)sA * 32 + j4);
            atomicAdd(&acc[wv][__float_as_uint(vA.x) & 127u], vA.x);
            atomicAdd(&acc[wv][__float_as_uint(vA.y) & 127u], vA.y);
            atomicAdd(&acc[wv][__float_as_uint(vA.z) & 127u], vA.z);
            atomicAdd(&acc[wv][__float_as_uint(vA.w) & 127u], vA.w);
        }
    }
    __syncthreads();
    if (node < n) {
        float dv = dvin[node];
        out[(size_t)node * 128 + lane] = acc[wv][lane] * dv + bg[lane];
        out[(size_t)node * 128 + lane + 64] = acc[wv][lane + 64] * dv + bg[lane + 64];
    }
}

// ---------------- GEMM [n,128] x [128,64] + bias -> d_out ----------------
__global__ __launch_bounds__(256, 4) void gemm_out64(const float* __restrict__ A,
                                                     const float* __restrict__ W,
                                                     const float* __restrict__ bias,
                                                     float* __restrict__ out, int n) {
    __shared__ float Ws[128][64];
    const int tid = threadIdx.x;
    const int rbase = blockIdx.x * 64;
    const int cc = tid & 15;
    const int r0 = (tid >> 4) * 4;
    const float* a_base = A + (size_t)(rbase + r0) * 128;
    float acc[4][4];
#pragma unroll
    for (int i = 0; i < 4; ++i) { acc[i][0] = 0.f; acc[i][1] = 0.f; acc[i][2] = 0.f; acc[i][3] = 0.f; }

#pragma unroll
    for (int q = 0; q < 8; ++q) {
        int f = q * 256 + tid;
        float4 v = *(const float4*)(W + (size_t)f * 4);
        *(float4*)&Ws[f >> 4][(f & 15) * 4] = v;
    }
    __syncthreads();
    for (int kq = 0; kq < 32; ++kq) {
        int k = kq * 4;
        float4 w0 = *(float4*)&Ws[k + 0][cc * 4];
        float4 w1 = *(float4*)&Ws[k + 1][cc * 4];
        float4 w2 = *(float4*)&Ws[k + 2][cc * 4];
        float4 w3 = *(float4*)&Ws[k + 3][cc * 4];
#pragma unroll
        for (int i = 0; i < 4; ++i) {
            float4 a = *(const float4*)(a_base + (size_t)i * 128 + k);
            acc[i][0] += a.x * w0.x + a.y * w1.x + a.z * w2.x + a.w * w3.x;
            acc[i][1] += a.x * w0.y + a.y * w1.y + a.z * w2.y + a.w * w3.y;
            acc[i][2] += a.x * w0.z + a.y * w1.z + a.z * w2.z + a.w * w3.z;
            acc[i][3] += a.x * w0.w + a.y * w1.w + a.z * w2.w + a.w * w3.w;
        }
    }
    float4 b4 = *(const float4*)(bias + cc * 4);
#pragma unroll
    for (int i = 0; i < 4; ++i) {
        int gr = rbase + r0 + i;
        if (gr < n) {
            float4 o = make_float4(acc[i][0] + b4.x, acc[i][1] + b4.y,
                                   acc[i][2] + b4.z, acc[i][3] + b4.w);
            *(float4*)(out + (size_t)gr * 64 + cc * 4) = o;
        }
    }
}

extern "C" void kernel_launch(void* const* d_in, const int* in_sizes, int n_in,
                              void* d_out, int out_size, void* d_ws, size_t ws_size,
                              hipStream_t stream) {
    const float* x     = (const float*)d_in[0];
    const int*   src   = (const int*)d_in[1];
    const int*   dst   = (const int*)d_in[2];
    const float* W_in  = (const float*)d_in[3];
    const float* b_in  = (const float*)d_in[4];
    const float* W1    = (const float*)d_in[5];
    const float* b1    = (const float*)d_in[6];
    const float* bg1   = (const float*)d_in[7];
    const float* W2    = (const float*)d_in[8];
    const float* b2    = (const float*)d_in[9];
    const float* bg2   = (const float*)d_in[10];
    const float* W_out = (const float*)d_in[11];
    const float* b_out = (const float*)d_in[12];
    float* out = (float*)d_out;

    char* p = (char*)d_ws;
    auto carve = [&](size_t bytes) {
        char* r = p;
        p += (bytes + 255) & ~(size_t)255;
        return r;
    };
    int*   cnt_out = (int*)carve((size_t)NN * 4);
    int*   cnt_in  = (int*)carve((size_t)NN * 4);
    float* dvout   = (float*)carve((size_t)(NN + 128) * 4);  // padded: gemm_maxk reads OOB rows
    float* dvin    = (float*)carve((size_t)NN * 4);
    int*   incl    = (int*)carve((size_t)NN * 4);
    int*   bsums   = (int*)carve(512 * 4);
    int*   boff    = (int*)carve(512 * 4);
    int*   row_off = (int*)carve((size_t)(NN + 1) * 4);
    int*   cursor  = (int*)carve((size_t)NN * 4);
    int*   csr_src = (int*)carve((size_t)EE * 4);
    float* hbuf    = (float*)carve((size_t)(NN + 128) * HIDF * 4);  // padded rows
    float* svals   = (float*)carve((size_t)NN * KSEL * 4);

    const int gN   = (NN + 255) / 256;   // 391
    const int gE   = (EE + 255) / 256;   // 6250
    const int gT   = (NN + 63) / 64;     // 1563 row tiles
    const int gAgg = (NN + 3) / 4;       // 25000

    hipMemsetAsync(cnt_out, 0, (size_t)NN * 4, stream);
    hipMemsetAsync(cnt_in, 0, (size_t)NN * 4, stream);
    hist_kernel<<<gE, 256, 0, stream>>>(src, dst, cnt_out, cnt_in, EE);
    scan_block<<<gN, 256, 0, stream>>>(cnt_in, incl, bsums, NN);
    scan_sums<<<1, 512, 0, stream>>>(bsums, boff, gN);
    finalize_offsets<<<gN, 256, 0, stream>>>(incl, boff, cnt_in, cnt_out, row_off, cursor,
                                             dvout, dvin, NN);
    csr_fill<<<gE, 256, 0, stream>>>(src, dst, cursor, csr_src, EE);

    gemm_relu<<<gT, 256, 0, stream>>>(x, W_in, b_in, hbuf, NN);

    gemm_maxk<<<gT, 256, 0, stream>>>(hbuf, W1, b1, dvout, svals, NN);
    agg_kernel<<<gAgg, 256, 0, stream>>>(svals, row_off, csr_src, dvin, bg1, hbuf, NN);

    gemm_maxk<<<gT, 256, 0, stream>>>(hbuf, W2, b2, dvout, svals, NN);
    agg_kernel<<<gAgg, 256, 0, stream>>>(svals, row_off, csr_src, dvin, bg2, hbuf, NN);

    gemm_out64<<<gT, 256, 0, stream>>>(hbuf, W_out, b_out, out, NN);
}

// Round 5
// 897.207 us; speedup vs baseline: 1.7612x; 1.4467x over previous
//
#include <hip/hip_runtime.h>

#define NN   100000
#define EE   1600000
#define HIDF 128
#define OUTF 64
#define KSEL 32

static __device__ __forceinline__ unsigned int sortable_key(float f) {
    unsigned int u = __float_as_uint(f);
    return (u & 0x80000000u) ? ~u : (u | 0x80000000u);
}

// ---------------- degree histogram ----------------
__global__ __launch_bounds__(256) void hist_kernel(const int* __restrict__ src,
                                                   const int* __restrict__ dst,
                                                   int* __restrict__ cnt_out,
                                                   int* __restrict__ cnt_in, int e) {
    int i = blockIdx.x * 256 + threadIdx.x;
    if (i < e) {
        atomicAdd(&cnt_out[src[i]], 1);
        atomicAdd(&cnt_in[dst[i]], 1);
    }
}

// ---------------- prefix scan (3 kernels) ----------------
__global__ __launch_bounds__(256) void scan_block(const int* __restrict__ cnt,
                                                  int* __restrict__ incl,
                                                  int* __restrict__ bsums, int n) {
    __shared__ int s[256];
    int t = threadIdx.x;
    int i = blockIdx.x * 256 + t;
    int v = (i < n) ? cnt[i] : 0;
    s[t] = v;
    __syncthreads();
    for (int off = 1; off < 256; off <<= 1) {
        int x = (t >= off) ? s[t - off] : 0;
        __syncthreads();
        s[t] += x;
        __syncthreads();
    }
    if (i < n) incl[i] = s[t];
    if (t == 255) bsums[blockIdx.x] = s[255];
}

__global__ __launch_bounds__(512) void scan_sums(const int* __restrict__ bsums,
                                                 int* __restrict__ boff, int nb) {
    __shared__ int s[512];
    int t = threadIdx.x;
    int v = (t < nb) ? bsums[t] : 0;
    s[t] = v;
    __syncthreads();
    for (int off = 1; off < 512; off <<= 1) {
        int x = (t >= off) ? s[t - off] : 0;
        __syncthreads();
        s[t] += x;
        __syncthreads();
    }
    boff[t] = s[t] - v;  // exclusive
}

__global__ __launch_bounds__(256) void finalize_offsets(const int* __restrict__ incl,
                                                        const int* __restrict__ boff,
                                                        const int* __restrict__ cnt_in,
                                                        const int* __restrict__ cnt_out,
                                                        int* __restrict__ row_off,
                                                        int* __restrict__ cursor,
                                                        float* __restrict__ dvo,
                                                        float* __restrict__ dvi, int n) {
    int i = blockIdx.x * 256 + threadIdx.x;
    if (i < n) {
        int ci = cnt_in[i];
        int val = incl[i] + boff[i >> 8];
        row_off[i + 1] = val;
        cursor[i] = val - ci;
        if (i == 0) row_off[0] = 0;
        dvo[i] = rsqrtf((float)max(cnt_out[i], 1));
        dvi[i] = rsqrtf((float)max(ci, 1));
    }
}

__global__ __launch_bounds__(256) void csr_fill(const int* __restrict__ src,
                                                const int* __restrict__ dst,
                                                int* __restrict__ cursor,
                                                int* __restrict__ csr, int e) {
    int i = blockIdx.x * 256 + threadIdx.x;
    if (i < e) {
        int d = dst[i];
        int pos = atomicAdd(&cursor[d], 1);
        csr[pos] = src[i];
    }
}

// ---------------- GEMM [n,128] x [128,128] + bias + ReLU ----------------
__global__ __launch_bounds__(256, 4) void gemm_relu(const float* __restrict__ A,
                                                    const float* __restrict__ W,
                                                    const float* __restrict__ bias,
                                                    float* __restrict__ out, int n) {
    __shared__ float Ws[64][128];
    const int tid = threadIdx.x;
    const int rbase = blockIdx.x * 64;
    const int cc = tid & 31;
    const int r0 = (tid >> 5) * 8;
    const bool full = (rbase + 64) <= n;
    const float* a_base = A + (size_t)(rbase + r0) * 128;
    float acc[8][4];
#pragma unroll
    for (int i = 0; i < 8; ++i) { acc[i][0] = 0.f; acc[i][1] = 0.f; acc[i][2] = 0.f; acc[i][3] = 0.f; }

    for (int half = 0; half < 2; ++half) {
        const int kb = half * 64;
        if (half) __syncthreads();
#pragma unroll
        for (int q = 0; q < 8; ++q) {
            int f = q * 256 + tid;
            float4 v = *(const float4*)(W + (size_t)kb * 128 + (size_t)f * 4);
            *(float4*)&Ws[f >> 5][(f & 31) * 4] = v;
        }
        __syncthreads();
        if (full) {
            for (int kq = 0; kq < 16; ++kq) {
                int k = kq * 4;
                float4 w0 = *(float4*)&Ws[k + 0][cc * 4];
                float4 w1 = *(float4*)&Ws[k + 1][cc * 4];
                float4 w2 = *(float4*)&Ws[k + 2][cc * 4];
                float4 w3 = *(float4*)&Ws[k + 3][cc * 4];
#pragma unroll
                for (int i = 0; i < 8; ++i) {
                    float4 a = *(const float4*)(a_base + (size_t)i * 128 + kb + k);
                    acc[i][0] += a.x * w0.x + a.y * w1.x + a.z * w2.x + a.w * w3.x;
                    acc[i][1] += a.x * w0.y + a.y * w1.y + a.z * w2.y + a.w * w3.y;
                    acc[i][2] += a.x * w0.z + a.y * w1.z + a.z * w2.z + a.w * w3.z;
                    acc[i][3] += a.x * w0.w + a.y * w1.w + a.z * w2.w + a.w * w3.w;
                }
            }
        } else {
            for (int kq = 0; kq < 16; ++kq) {
                int k = kq * 4;
                float4 w0 = *(float4*)&Ws[k + 0][cc * 4];
                float4 w1 = *(float4*)&Ws[k + 1][cc * 4];
                float4 w2 = *(float4*)&Ws[k + 2][cc * 4];
                float4 w3 = *(float4*)&Ws[k + 3][cc * 4];
#pragma unroll
                for (int i = 0; i < 8; ++i) {
                    float4 a = make_float4(0.f, 0.f, 0.f, 0.f);
                    if (rbase + r0 + i < n) a = *(const float4*)(a_base + (size_t)i * 128 + kb + k);
                    acc[i][0] += a.x * w0.x + a.y * w1.x + a.z * w2.x + a.w * w3.x;
                    acc[i][1] += a.x * w0.y + a.y * w1.y + a.z * w2.y + a.w * w3.y;
                    acc[i][2] += a.x * w0.z + a.y * w1.z + a.z * w2.z + a.w * w3.z;
                    acc[i][3] += a.x * w0.w + a.y * w1.w + a.z * w2.w + a.w * w3.w;
                }
            }
        }
    }
    float4 b4 = *(const float4*)(bias + cc * 4);
#pragma unroll
    for (int i = 0; i < 8; ++i) {
        int gr = rbase + r0 + i;
        if (gr < n) {
            float4 o = make_float4(fmaxf(acc[i][0] + b4.x, 0.f), fmaxf(acc[i][1] + b4.y, 0.f),
                                   fmaxf(acc[i][2] + b4.z, 0.f), fmaxf(acc[i][3] + b4.w, 0.f));
            *(float4*)(out + (size_t)gr * 128 + cc * 4) = o;
        }
    }
}

// ---------------- GEMM + bias + MaxK(top-32) fused in-register ----------------
__global__ __launch_bounds__(256, 4) void gemm_maxk(const float* __restrict__ A,
                                                    const float* __restrict__ W,
                                                    const float* __restrict__ bias,
                                                    const float* __restrict__ dvout,
                                                    float* __restrict__ svals, int n) {
    __shared__ float Ws[64][128];
    const int tid = threadIdx.x;
    const int rbase = blockIdx.x * 64;
    const int cc = tid & 31;
    const int r0 = (tid >> 5) * 8;
    const float* a_base = A + (size_t)(rbase + r0) * 128;
    float acc[8][4];
#pragma unroll
    for (int i = 0; i < 8; ++i) { acc[i][0] = 0.f; acc[i][1] = 0.f; acc[i][2] = 0.f; acc[i][3] = 0.f; }

    for (int half = 0; half < 2; ++half) {
        const int kb = half * 64;
        if (half) __syncthreads();
#pragma unroll
        for (int q = 0; q < 8; ++q) {
            int f = q * 256 + tid;
            float4 v = *(const float4*)(W + (size_t)kb * 128 + (size_t)f * 4);
            *(float4*)&Ws[f >> 5][(f & 31) * 4] = v;
        }
        __syncthreads();
        for (int kq = 0; kq < 16; ++kq) {
            int k = kq * 4;
            float4 w0 = *(float4*)&Ws[k + 0][cc * 4];
            float4 w1 = *(float4*)&Ws[k + 1][cc * 4];
            float4 w2 = *(float4*)&Ws[k + 2][cc * 4];
            float4 w3 = *(float4*)&Ws[k + 3][cc * 4];
#pragma unroll
            for (int i = 0; i < 8; ++i) {
                float4 a = *(const float4*)(a_base + (size_t)i * 128 + kb + k);
                acc[i][0] += a.x * w0.x + a.y * w1.x + a.z * w2.x + a.w * w3.x;
                acc[i][1] += a.x * w0.y + a.y * w1.y + a.z * w2.y + a.w * w3.y;
                acc[i][2] += a.x * w0.z + a.y * w1.z + a.z * w2.z + a.w * w3.z;
                acc[i][3] += a.x * w0.w + a.y * w1.w + a.z * w2.w + a.w * w3.w;
            }
        }
    }

    // ---- fused MaxK select ----
    const int lane = tid & 63;
    const int wvi = tid >> 6;
    const bool up = lane >= 32;
    const unsigned lt32 = (1u << (lane & 31)) - 1u;
    float4 b4 = *(const float4*)(bias + cc * 4);

#pragma unroll 1
    for (int i = 0; i < 8; ++i) {
        int row = rbase + 16 * wvi + i + (up ? 8 : 0);
        float v0 = acc[i][0] + b4.x;
        float v1 = acc[i][1] + b4.y;
        float v2 = acc[i][2] + b4.z;
        float v3 = acc[i][3] + b4.w;
        unsigned k0 = sortable_key(v0), k1 = sortable_key(v1);
        unsigned k2 = sortable_key(v2), k3 = sortable_key(v3);
        unsigned prefL = 0u, prefU = 0u;
        for (int bit = 31; bit >= 8; --bit) {
            unsigned cL = prefL | (1u << bit);
            unsigned cU = prefU | (1u << bit);
            unsigned myc = up ? cU : cL;
            unsigned long long b0 = __ballot(k0 >= myc);
            unsigned long long b1 = __ballot(k1 >= myc);
            unsigned long long b2 = __ballot(k2 >= myc);
            unsigned long long b3 = __ballot(k3 >= myc);
            int cntL = __popc((unsigned)b0) + __popc((unsigned)b1) +
                       __popc((unsigned)b2) + __popc((unsigned)b3);
            int cntU = __popc((unsigned)(b0 >> 32)) + __popc((unsigned)(b1 >> 32)) +
                       __popc((unsigned)(b2 >> 32)) + __popc((unsigned)(b3 >> 32));
            prefL = (cntL >= KSEL) ? cL : prefL;
            prefU = (cntU >= KSEL) ? cU : prefU;
        }
        unsigned myp = up ? prefU : prefL;
        unsigned kb0 = k0 & 0xFFFFFF00u, kb1 = k1 & 0xFFFFFF00u;
        unsigned kb2 = k2 & 0xFFFFFF00u, kb3 = k3 & 0xFFFFFF00u;
        unsigned long long g0 = __ballot(kb0 > myp), g1 = __ballot(kb1 > myp);
        unsigned long long g2 = __ballot(kb2 > myp), g3 = __ballot(kb3 > myp);
        unsigned long long e0 = __ballot(kb0 == myp), e1 = __ballot(kb1 == myp);
        unsigned long long e2 = __ballot(kb2 == myp), e3 = __ballot(kb3 == myp);
        unsigned gh0 = up ? (unsigned)(g0 >> 32) : (unsigned)g0;
        unsigned gh1 = up ? (unsigned)(g1 >> 32) : (unsigned)g1;
        unsigned gh2 = up ? (unsigned)(g2 >> 32) : (unsigned)g2;
        unsigned gh3 = up ? (unsigned)(g3 >> 32) : (unsigned)g3;
        unsigned eh0 = up ? (unsigned)(e0 >> 32) : (unsigned)e0;
        unsigned eh1 = up ? (unsigned)(e1 >> 32) : (unsigned)e1;
        unsigned eh2 = up ? (unsigned)(e2 >> 32) : (unsigned)e2;
        unsigned eh3 = up ? (unsigned)(e3 >> 32) : (unsigned)e3;
        int m = __popc(gh0) + __popc(gh1) + __popc(gh2) + __popc(gh3);
        int need = KSEL - m;
        int gpos = __popc(gh0 & lt32) + __popc(gh1 & lt32) + __popc(gh2 & lt32) + __popc(gh3 & lt32);
        int epos = __popc(eh0 & lt32) + __popc(eh1 & lt32) + __popc(eh2 & lt32) + __popc(eh3 & lt32);
        bool ok = row < n;
        float ds = dvout[row];
        size_t base = (size_t)row * 32;
        unsigned cbit = (unsigned)(lane & 31);
        // j = 0
        {
            int slot = -1;
            if (kb0 > myp) slot = gpos;
            else if (kb0 == myp && epos < need) slot = m + epos;
            if (slot >= 0 && ok) {
                unsigned u = (__float_as_uint(v0 * ds) & 0xFFFFFF80u) | (unsigned)(cc * 4 + 0);
                svals[base + slot] = __uint_as_float(u);
            }
            gpos += (gh0 >> cbit) & 1u;
            epos += (eh0 >> cbit) & 1u;
        }
        // j = 1
        {
            int slot = -1;
            if (kb1 > myp) slot = gpos;
            else if (kb1 == myp && epos < need) slot = m + epos;
            if (slot >= 0 && ok) {
                unsigned u = (__float_as_uint(v1 * ds) & 0xFFFFFF80u) | (unsigned)(cc * 4 + 1);
                svals[base + slot] = __uint_as_float(u);
            }
            gpos += (gh1 >> cbit) & 1u;
            epos += (eh1 >> cbit) & 1u;
        }
        // j = 2
        {
            int slot = -1;
            if (kb2 > myp) slot = gpos;
            else if (kb2 == myp && epos < need) slot = m + epos;
            if (slot >= 0 && ok) {
                unsigned u = (__float_as_uint(v2 * ds) & 0xFFFFFF80u) | (unsigned)(cc * 4 + 2);
                svals[base + slot] = __uint_as_float(u);
            }
            gpos += (gh2 >> cbit) & 1u;
            epos += (eh2 >> cbit) & 1u;
        }
        // j = 3
        {
            int slot = -1;
            if (kb3 > myp) slot = gpos;
            else if (kb3 == myp && epos < need) slot = m + epos;
            if (slot >= 0 && ok) {
                unsigned u = (__float_as_uint(v3 * ds) & 0xFFFFFF80u) | (unsigned)(cc * 4 + 3);
                svals[base + slot] = __uint_as_float(u);
            }
        }
    }
}

// ---------------- CSR aggregation: atomic-free ----------------
// One wave per dst node; two 32-lane groups each own a PRIVATE 128-float LDS
// accumulator and process one edge per step. Within an edge the 32 top-k
// feature indices are distinct -> plain ds_read/add/ds_write RMW is race-free
// (no same-word collision within an instruction; cross-iteration ordering is
// guaranteed by per-wave in-order DS execution). Replaces 32 atomic lane-ops
// per edge (the round-4 bottleneck: ~200 cyc per wave-atomic instr).
__global__ __launch_bounds__(256) void agg_kernel(const float* __restrict__ svals,
                                                  const int* __restrict__ row_off,
                                                  const int* __restrict__ csr_src,
                                                  const float* __restrict__ dvin,
                                                  const float* __restrict__ bg,
                                                  float* __restrict__ out, int n) {
    __shared__ float acc[4][2][128];  // [wave][slot][feature], wave-private
    const int wv = threadIdx.x >> 6;
    const int lane = threadIdx.x & 63;
    const int sub = lane >> 5;   // which edge slot
    const int j = lane & 31;     // entry within record
    const int node = blockIdx.x * 4 + wv;
    float* base0 = &acc[wv][0][0];
    base0[lane] = 0.f;
    base0[lane + 64] = 0.f;
    base0[lane + 128] = 0.f;
    base0[lane + 192] = 0.f;
    if (node < n) {
        int s0 = row_off[node], s1 = row_off[node + 1];
        float* Ac = &acc[wv][sub][0];
        int e = s0 + sub;
        // 2 edges per wave-step (one per 32-lane group), unrolled x2 for MLP
        for (; e + 2 < s1; e += 4) {
            int sA = csr_src[e];
            int sB = csr_src[e + 2];
            float vA = svals[(size_t)sA * 32 + j];
            float vB = svals[(size_t)sB * 32 + j];
            int fA = (int)(__float_as_uint(vA) & 127u);
            Ac[fA] += vA;
            int fB = (int)(__float_as_uint(vB) & 127u);
            Ac[fB] += vB;
        }
        for (; e < s1; e += 2) {
            int sA = csr_src[e];
            float vA = svals[(size_t)sA * 32 + j];
            int fA = (int)(__float_as_uint(vA) & 127u);
            Ac[fA] += vA;
        }
    }
    // wave-private LDS: no barrier needed; per-wave DS ordering covers RAW.
    if (node < n) {
        float dv = dvin[node];
        float r0 = acc[wv][0][lane] + acc[wv][1][lane];
        float r1 = acc[wv][0][lane + 64] + acc[wv][1][lane + 64];
        out[(size_t)node * 128 + lane] = r0 * dv + bg[lane];
        out[(size_t)node * 128 + lane + 64] = r1 * dv + bg[lane + 64];
    }
}

// ---------------- GEMM [n,128] x [128,64] + bias -> d_out ----------------
__global__ __launch_bounds__(256, 4) void gemm_out64(const float* __restrict__ A,
                                                     const float* __restrict__ W,
                                                     const float* __restrict__ bias,
                                                     float* __restrict__ out, int n) {
    __shared__ float Ws[128][64];
    const int tid = threadIdx.x;
    const int rbase = blockIdx.x * 64;
    const int cc = tid & 15;
    const int r0 = (tid >> 4) * 4;
    const float* a_base = A + (size_t)(rbase + r0) * 128;
    float acc[4][4];
#pragma unroll
    for (int i = 0; i < 4; ++i) { acc[i][0] = 0.f; acc[i][1] = 0.f; acc[i][2] = 0.f; acc[i][3] = 0.f; }

#pragma unroll
    for (int q = 0; q < 8; ++q) {
        int f = q * 256 + tid;
        float4 v = *(const float4*)(W + (size_t)f * 4);
        *(float4*)&Ws[f >> 4][(f & 15) * 4] = v;
    }
    __syncthreads();
    for (int kq = 0; kq < 32; ++kq) {
        int k = kq * 4;
        float4 w0 = *(float4*)&Ws[k + 0][cc * 4];
        float4 w1 = *(float4*)&Ws[k + 1][cc * 4];
        float4 w2 = *(float4*)&Ws[k + 2][cc * 4];
        float4 w3 = *(float4*)&Ws[k + 3][cc * 4];
#pragma unroll
        for (int i = 0; i < 4; ++i) {
            float4 a = *(const float4*)(a_base + (size_t)i * 128 + k);
            acc[i][0] += a.x * w0.x + a.y * w1.x + a.z * w2.x + a.w * w3.x;
            acc[i][1] += a.x * w0.y + a.y * w1.y + a.z * w2.y + a.w * w3.y;
            acc[i][2] += a.x * w0.z + a.y * w1.z + a.z * w2.z + a.w * w3.z;
            acc[i][3] += a.x * w0.w + a.y * w1.w + a.z * w2.w + a.w * w3.w;
        }
    }
    float4 b4 = *(const float4*)(bias + cc * 4);
#pragma unroll
    for (int i = 0; i < 4; ++i) {
        int gr = rbase + r0 + i;
        if (gr < n) {
            float4 o = make_float4(acc[i][0] + b4.x, acc[i][1] + b4.y,
                                   acc[i][2] + b4.z, acc[i][3] + b4.w);
            *(float4*)(out + (size_t)gr * 64 + cc * 4) = o;
        }
    }
}

extern "C" void kernel_launch(void* const* d_in, const int* in_sizes, int n_in,
                              void* d_out, int out_size, void* d_ws, size_t ws_size,
                              hipStream_t stream) {
    const float* x     = (const float*)d_in[0];
    const int*   src   = (const int*)d_in[1];
    const int*   dst   = (const int*)d_in[2];
    const float* W_in  = (const float*)d_in[3];
    const float* b_in  = (const float*)d_in[4];
    const float* W1    = (const float*)d_in[5];
    const float* b1    = (const float*)d_in[6];
    const float* bg1   = (const float*)d_in[7];
    const float* W2    = (const float*)d_in[8];
    const float* b2    = (const float*)d_in[9];
    const float* bg2   = (const float*)d_in[10];
    const float* W_out = (const float*)d_in[11];
    const float* b_out = (const float*)d_in[12];
    float* out = (float*)d_out;

    char* p = (char*)d_ws;
    auto carve = [&](size_t bytes) {
        char* r = p;
        p += (bytes + 255) & ~(size_t)255;
        return r;
    };
    int*   cnt_out = (int*)carve((size_t)NN * 4);
    int*   cnt_in  = (int*)carve((size_t)NN * 4);
    float* dvout   = (float*)carve((size_t)(NN + 128) * 4);  // padded: gemm_maxk reads OOB rows
    float* dvin    = (float*)carve((size_t)NN * 4);
    int*   incl    = (int*)carve((size_t)NN * 4);
    int*   bsums   = (int*)carve(512 * 4);
    int*   boff    = (int*)carve(512 * 4);
    int*   row_off = (int*)carve((size_t)(NN + 1) * 4);
    int*   cursor  = (int*)carve((size_t)NN * 4);
    int*   csr_src = (int*)carve((size_t)EE * 4);
    float* hbuf    = (float*)carve((size_t)(NN + 128) * HIDF * 4);  // padded rows
    float* svals   = (float*)carve((size_t)NN * KSEL * 4);

    const int gN   = (NN + 255) / 256;   // 391
    const int gE   = (EE + 255) / 256;   // 6250
    const int gT   = (NN + 63) / 64;     // 1563 row tiles
    const int gAgg = (NN + 3) / 4;       // 25000

    hipMemsetAsync(cnt_out, 0, (size_t)NN * 4, stream);
    hipMemsetAsync(cnt_in, 0, (size_t)NN * 4, stream);
    hist_kernel<<<gE, 256, 0, stream>>>(src, dst, cnt_out, cnt_in, EE);
    scan_block<<<gN, 256, 0, stream>>>(cnt_in, incl, bsums, NN);
    scan_sums<<<1, 512, 0, stream>>>(bsums, boff, gN);
    finalize_offsets<<<gN, 256, 0, stream>>>(incl, boff, cnt_in, cnt_out, row_off, cursor,
                                             dvout, dvin, NN);
    csr_fill<<<gE, 256, 0, stream>>>(src, dst, cursor, csr_src, EE);

    gemm_relu<<<gT, 256, 0, stream>>>(x, W_in, b_in, hbuf, NN);

    gemm_maxk<<<gT, 256, 0, stream>>>(hbuf, W1, b1, dvout, svals, NN);
    agg_kernel<<<gAgg, 256, 0, stream>>>(svals, row_off, csr_src, dvin, bg1, hbuf, NN);

    gemm_maxk<<<gT, 256, 0, stream>>>(hbuf, W2, b2, dvout, svals, NN);
    agg_kernel<<<gAgg, 256, 0, stream>>>(svals, row_off, csr_src, dvin, bg2, hbuf, NN);

    gemm_out64<<<gT, 256, 0, stream>>>(hbuf, W_out, b_out, out, NN);
}